// Round 15
// baseline (56.051 us; speedup 1.0000x reference)
//
#include <hip/hip_runtime.h>
#include <hip/hip_fp16.h>

#define NTHREADS 256
#define NBLOCKS 1024
#define FB_NBLOCKS 2048
#define NB 1024          // lerp intervals
#define NBP 1040         // padded stride for f32 node scratch

// Folded constants (same derivation as R9/R13):
//   KTOT = sqrt(2)*1.14136*e^2 ; CL_l = PATH_C_l * 0.25 / sqrt(10)
//   SH scales folded into packed node values; w_l(r)*CL_l in the r-LUT.
#define KTOT 11.9269705f
#define CL0  0.04564355f
#define CL1  0.02635231f
#define CL2  0.02041241f
#define S3   1.7320508f
#define S5   2.2360680f

__device__ __forceinline__ float fast_rcp(float x) { return __builtin_amdgcn_rcpf(x); }

// ---------- prep 1: node_feats [N][9] f32 -> 16B/node packed record (PROVEN R13) ----------
// bits [0..112): f1s..f8s as fp14 (fp16 rounded, >>2) at 14-bit stride; [112..128): f0 fp16
__global__ __launch_bounds__(256) void pack_feats_14(
    const float* __restrict__ nf, uint4* __restrict__ tab, int n_nodes)
{
    const int n = blockIdx.x * 256 + threadIdx.x;
    if (n >= n_nodes) return;
    const float* f = nf + 9 * (size_t)n;
    const float scale[9] = { 1.0f, S3, S3, S3, S5 * S3, S5 * S3, S5, S5 * S3,
                             0.5f * S5 * S3 };
    unsigned short hs[9];
#pragma unroll
    for (int i = 0; i < 9; ++i) {
        const __half h = __float2half_rn(f[i] * scale[i]);
        hs[i] = *reinterpret_cast<const unsigned short*>(&h);
    }
    unsigned long long c[9];
#pragma unroll
    for (int i = 1; i < 9; ++i)
        c[i] = (unsigned long long)(((unsigned)hs[i] + 2u) >> 2) & 0x3FFFull;
    const unsigned long long lo =
        c[1] | (c[2] << 14) | (c[3] << 28) | (c[4] << 42) | (c[5] << 56);
    const unsigned long long hi =
        (c[5] >> 8) | (c[6] << 6) | (c[7] << 20) | (c[8] << 34) |
        ((unsigned long long)hs[0] << 48);
    tab[n] = make_uint4((unsigned)lo, (unsigned)(lo >> 32),
                        (unsigned)hi, (unsigned)(hi >> 32));
}

// ---------- prep 2a: w_l(r)*CL_l at nodes r=i/NB, i=0..NB (f32 scratch; identical math) ----------
__global__ __launch_bounds__(256) void build_wtable_kernel(
    const float* __restrict__ W1, const float* __restrict__ W2,
    float* __restrict__ wtabf)   // [3][NBP]
{
    const int idx = blockIdx.x * 256 + threadIdx.x;
    if (idx > NB) return;
    const float r = (float)idx * (1.0f / (float)NB);

    const float t    = 11.0f * r;
    const int   k0   = (int)t;
    const float frac = t - (float)k0;
    float ea = 0.0f, eb = 0.0f;
    if (k0 >= 1 && k0 <= 10) {
        const float da = fmaf(-frac, frac, 1.0f);
        if (da > 0.0226f) ea = KTOT * __expf(-2.0f * fast_rcp(da));
    }
    if (k0 <= 9) {
        const float db = frac * (2.0f - frac);
        if (db > 0.0226f) eb = KTOT * __expf(-2.0f * fast_rcp(db));
    }
    const int ra = min(max(k0 - 1, 0), 9);
    const int rb = min(k0, 9);

    float w0 = 0.0f, w1 = 0.0f, w2 = 0.0f;
#pragma unroll
    for (int j = 0; j < 16; ++j) {
        const float h = fmaxf(fmaf(ea, W1[ra * 16 + j], eb * W1[rb * 16 + j]), 0.0f);
        w0 = fmaf(h, W2[j * 3 + 0], w0);
        w1 = fmaf(h, W2[j * 3 + 1], w1);
        w2 = fmaf(h, W2[j * 3 + 2], w2);
    }
    wtabf[idx]           = w0 * CL0;
    wtabf[NBP + idx]     = w1 * CL1;
    wtabf[2 * NBP + idx] = w2 * CL2;
}

// ---------- prep 2b: per-interval 16B records {b0,b1,b2, d0,d1,d2} as fp16 ----------
__global__ __launch_bounds__(256) void build_wrec_kernel(
    const float* __restrict__ wtabf, uint4* __restrict__ wrec)
{
    const int i = blockIdx.x * 256 + threadIdx.x;
    if (i >= NB) return;
    const float w0a = wtabf[i],           w0b = wtabf[i + 1];
    const float w1a = wtabf[NBP + i],     w1b = wtabf[NBP + i + 1];
    const float w2a = wtabf[2 * NBP + i], w2b = wtabf[2 * NBP + i + 1];
    auto hbits = [](float v) -> unsigned {
        const __half h = __float2half_rn(v);
        return (unsigned)*reinterpret_cast<const unsigned short*>(&h);
    };
    const unsigned b0 = hbits(w0a), b1 = hbits(w1a), b2 = hbits(w2a);
    const unsigned d0 = hbits(w0b - w0a), d1 = hbits(w1b - w1a), d2 = hbits(w2b - w2a);
    wrec[i] = make_uint4(b0 | (b1 << 16), b2 | (d0 << 16), d1 | (d2 << 16), 0u);
}

// fp14/fp16 decode
__device__ __forceinline__ float cvt14(unsigned c) {
    __half_raw hr; hr.x = (unsigned short)(c << 2);
    return __half2float(*reinterpret_cast<const __half*>(&hr));
}
__device__ __forceinline__ float cvt16(unsigned c) {
    __half_raw hr; hr.x = (unsigned short)(c & 0xFFFFu);
    return __half2float(*reinterpret_cast<const __half*>(&hr));
}
__device__ __forceinline__ unsigned alignb(unsigned hi, unsigned lo, int s) {
    return (lo >> s) | (hi << (32 - s));
}

// ---------- per-edge term: one LDS b128 LUT read + packed node record g ----------
__device__ __forceinline__ float edge_term(
    float vx, float vy, float vz, uint4 g, const uint4* __restrict__ swq)
{
    const float r2 = fmaf(vx, vx, fmaf(vy, vy, vz * vz));
    const float rs = rsqrtf(fmaxf(r2, 1e-24f));
    const float r  = r2 * rs;
    const float x = vx * rs, y = vy * rs, z = vz * rs;

    const float tb = fminf(r, 1.0f) * (float)NB;
    const int   i  = min((int)tb, NB - 1);
    const float fb = tb - (float)i;
    const uint4 q = swq[i];   // single ds_read_b128
    // q.x = b0|b1<<16 ; q.y = b2|d0<<16 ; q.z = d1|d2<<16
    const float wv0 = fmaf(fb, cvt16(q.y >> 16), cvt16(q.x));
    const float wv1 = fmaf(fb, cvt16(q.z),       cvt16(q.x >> 16));
    const float wv2 = fmaf(fb, cvt16(q.z >> 16), cvt16(q.y));

    // unpack 9 node values from 128 bits (PROVEN R13)
    const float fv1 = cvt14(g.x & 0x3FFFu);
    const float fv2 = cvt14((g.x >> 14) & 0x3FFFu);
    const float fv3 = cvt14(alignb(g.y, g.x, 28) & 0x3FFFu);
    const float fv4 = cvt14((g.y >> 10) & 0x3FFFu);
    const float fv5 = cvt14(alignb(g.z, g.y, 24) & 0x3FFFu);
    const float fv6 = cvt14((g.z >> 6) & 0x3FFFu);
    const float fv7 = cvt14(alignb(g.w, g.z, 20) & 0x3FFFu);
    const float fv8 = cvt14((g.w >> 2) & 0x3FFFu);
    const float f0  = cvt16(g.w >> 16);

    const float dots0 = f0;
    const float dots1 = fmaf(fv1, x, fmaf(fv2, y, fv3 * z));
    const float xx = x * x, yy = y * y, zz = z * z;
    const float dots2 = fmaf(fv4, x * z, fmaf(fv5, x * y,
                        fmaf(fv6, fmaf(-0.5f, xx + zz, yy),
                        fmaf(fv7, y * z, fv8 * (zz - xx)))));

    return fmaf(wv0, dots0, fmaf(wv1, dots1, wv2 * dots2));
}

// ---------- main: 1024x256 grid-stride, 8 edges/iter, 1 gather + 1 LDS op per edge ----------
__global__ __launch_bounds__(NTHREADS) void edge_sum_p14w(
    const float4* __restrict__ ev4,
    const int4*   __restrict__ src4,
    const uint4*  __restrict__ tab,
    const uint4*  __restrict__ wrec,
    float*        __restrict__ block_sums,
    int n_edges)
{
    __shared__ uint4 swq[NB];   // 16 KB
    const int tid = threadIdx.x;
#pragma unroll
    for (int i = tid; i < NB; i += NTHREADS) swq[i] = wrec[i];
    __syncthreads();

    float acc = 0.0f;
    const int n_units = (n_edges + 7) >> 3;
    const int stride = gridDim.x * blockDim.x;
    for (int u = blockIdx.x * blockDim.x + tid; u < n_units; u += stride) {
        const int e0 = u << 3;
        if (e0 + 8 <= n_edges) {
            const float4 v0 = ev4[6 * (size_t)u + 0];
            const float4 v1 = ev4[6 * (size_t)u + 1];
            const float4 v2 = ev4[6 * (size_t)u + 2];
            const float4 v3 = ev4[6 * (size_t)u + 3];
            const float4 v4 = ev4[6 * (size_t)u + 4];
            const float4 v5 = ev4[6 * (size_t)u + 5];
            const int4 sA = src4[2 * (size_t)u + 0];
            const int4 sB = src4[2 * (size_t)u + 1];
            const uint4 g0 = tab[sA.x];
            const uint4 g1 = tab[sA.y];
            const uint4 g2 = tab[sA.z];
            const uint4 g3 = tab[sA.w];
            const uint4 g4 = tab[sB.x];
            const uint4 g5 = tab[sB.y];
            const uint4 g6 = tab[sB.z];
            const uint4 g7 = tab[sB.w];
            acc += edge_term(v0.x, v0.y, v0.z, g0, swq);
            acc += edge_term(v0.w, v1.x, v1.y, g1, swq);
            acc += edge_term(v1.z, v1.w, v2.x, g2, swq);
            acc += edge_term(v2.y, v2.z, v2.w, g3, swq);
            acc += edge_term(v3.x, v3.y, v3.z, g4, swq);
            acc += edge_term(v3.w, v4.x, v4.y, g5, swq);
            acc += edge_term(v4.z, v4.w, v5.x, g6, swq);
            acc += edge_term(v5.y, v5.z, v5.w, g7, swq);
        } else {
            const float* evf  = reinterpret_cast<const float*>(ev4);
            const int*   srci = reinterpret_cast<const int*>(src4);
            for (int e = e0; e < n_edges; ++e) {
                acc += edge_term(evf[3 * (size_t)e], evf[3 * (size_t)e + 1],
                                 evf[3 * (size_t)e + 2], tab[srci[e]], swq);
            }
        }
    }

    // deterministic block reduction
#pragma unroll
    for (int off = 1; off < 64; off <<= 1)
        acc += __shfl_xor(acc, off, 64);
    __shared__ float wsum[NTHREADS / 64];
    const int lane = tid & 63, wid = tid >> 6;
    if (lane == 0) wsum[wid] = acc;
    __syncthreads();
    if (tid == 0) {
        float ssum = 0.0f;
#pragma unroll
        for (int w = 0; w < NTHREADS / 64; ++w) ssum += wsum[w];
        block_sums[blockIdx.x] = ssum;
    }
}

// ---------- fallback (round-2 proven path, exact math, f32 scalar gather) ----------
__global__ __launch_bounds__(NTHREADS) void edge_sum_fallback(
    const float* __restrict__ node_feats,
    const float* __restrict__ edge_vec,
    const float* __restrict__ W1,
    const float* __restrict__ W2,
    const int*   __restrict__ edge_src,
    float*       __restrict__ block_sums,
    int n_edges)
{
    __shared__ float4 sW1[10][5];
    float* sW1f = reinterpret_cast<float*>(sW1);
    const int tid = threadIdx.x;
    if (tid < 160) {
        sW1f[(tid >> 4) * 20 + (tid & 15)] = W1[tid];
    } else if (tid < 200) {
        const int i = tid - 160;
        sW1f[(i >> 2) * 20 + 16 + (i & 3)] = 0.0f;
    }
    __syncthreads();

    float w2r[16][3];
#pragma unroll
    for (int j = 0; j < 16; ++j) {
        w2r[j][0] = W2[j * 3 + 0] * CL0;
        w2r[j][1] = W2[j * 3 + 1] * CL1;
        w2r[j][2] = W2[j * 3 + 2] * CL2;
    }

    float acc = 0.0f;
    const int stride = gridDim.x * blockDim.x;
    for (int e = blockIdx.x * blockDim.x + tid; e < n_edges; e += stride) {
        const float vx = edge_vec[3 * (size_t)e + 0];
        const float vy = edge_vec[3 * (size_t)e + 1];
        const float vz = edge_vec[3 * (size_t)e + 2];
        const int   src = edge_src[e];
        const float* f = node_feats + 9 * (size_t)src;
        const float r2 = fmaf(vx, vx, fmaf(vy, vy, vz * vz));
        const float rs = rsqrtf(fmaxf(r2, 1e-24f));
        const float r  = r2 * rs;
        const float x = vx * rs, y = vy * rs, z = vz * rs;
        const float t    = 11.0f * r;
        const int   k0   = (int)t;
        const float frac = t - (float)k0;
        float ea = 0.0f, eb = 0.0f;
        if (k0 >= 1 && k0 <= 10) {
            const float da = fmaf(-frac, frac, 1.0f);
            if (da > 0.0226f) ea = KTOT * __expf(-2.0f * fast_rcp(da));
        }
        if (k0 <= 9) {
            const float db = frac * (2.0f - frac);
            if (db > 0.0226f) eb = KTOT * __expf(-2.0f * fast_rcp(db));
        }
        const int ra = min(max(k0 - 1, 0), 9);
        const int rb = min(k0, 9);
        const float4* rowA = &sW1[ra][0];
        const float4* rowB = &sW1[rb][0];
        float wv0 = 0.0f, wv1 = 0.0f, wv2 = 0.0f;
#pragma unroll
        for (int q = 0; q < 4; ++q) {
            const float4 A = rowA[q];
            const float4 B = rowB[q];
            float h;
            h = fmaxf(fmaf(ea, A.x, eb * B.x), 0.0f);
            wv0 = fmaf(h, w2r[4 * q + 0][0], wv0); wv1 = fmaf(h, w2r[4 * q + 0][1], wv1); wv2 = fmaf(h, w2r[4 * q + 0][2], wv2);
            h = fmaxf(fmaf(ea, A.y, eb * B.y), 0.0f);
            wv0 = fmaf(h, w2r[4 * q + 1][0], wv0); wv1 = fmaf(h, w2r[4 * q + 1][1], wv1); wv2 = fmaf(h, w2r[4 * q + 1][2], wv2);
            h = fmaxf(fmaf(ea, A.z, eb * B.z), 0.0f);
            wv0 = fmaf(h, w2r[4 * q + 2][0], wv0); wv1 = fmaf(h, w2r[4 * q + 2][1], wv1); wv2 = fmaf(h, w2r[4 * q + 2][2], wv2);
            h = fmaxf(fmaf(ea, A.w, eb * B.w), 0.0f);
            wv0 = fmaf(h, w2r[4 * q + 3][0], wv0); wv1 = fmaf(h, w2r[4 * q + 3][1], wv1); wv2 = fmaf(h, w2r[4 * q + 3][2], wv2);
        }
        const float f0 = f[0], f1 = f[1], f2 = f[2], f3 = f[3], f4 = f[4];
        const float f5 = f[5], f6 = f[6], f7 = f[7], f8 = f[8];
        const float dots0 = f0;
        const float dots1 = S3 * fmaf(f1, x, fmaf(f2, y, f3 * z));
        const float xx = x * x, yy = y * y, zz = z * z;
        const float sh20 = S5 * S3 * x * z;
        const float sh21 = S5 * S3 * x * y;
        const float sh22 = S5 * (yy - 0.5f * (xx + zz));
        const float sh23 = S5 * S3 * y * z;
        const float sh24 = S5 * 0.5f * S3 * (zz - xx);
        const float dots2 = fmaf(f4, sh20, fmaf(f5, sh21, fmaf(f6, sh22, fmaf(f7, sh23, f8 * sh24))));
        acc = fmaf(wv0, dots0, acc);
        acc = fmaf(wv1, dots1, acc);
        acc = fmaf(wv2, dots2, acc);
    }
#pragma unroll
    for (int off = 1; off < 64; off <<= 1)
        acc += __shfl_xor(acc, off, 64);
    __shared__ float wsum[NTHREADS / 64];
    const int lane = tid & 63, wid = tid >> 6;
    if (lane == 0) wsum[wid] = acc;
    __syncthreads();
    if (tid == 0) {
        float ssum = 0.0f;
#pragma unroll
        for (int w = 0; w < NTHREADS / 64; ++w) ssum += wsum[w];
        block_sums[blockIdx.x] = ssum;
    }
}

__global__ __launch_bounds__(256) void final_reduce_kernel(
    const float* __restrict__ block_sums, float* __restrict__ out, int n)
{
    const int tid = threadIdx.x;
    float acc = 0.0f;
    for (int i = tid; i < n; i += 256) acc += block_sums[i];
#pragma unroll
    for (int off = 1; off < 64; off <<= 1)
        acc += __shfl_xor(acc, off, 64);
    __shared__ float wsum[4];
    if ((tid & 63) == 0) wsum[tid >> 6] = acc;
    __syncthreads();
    if (tid == 0) out[0] = wsum[0] + wsum[1] + wsum[2] + wsum[3];
}

extern "C" void kernel_launch(void* const* d_in, const int* in_sizes, int n_in,
                              void* d_out, int out_size, void* d_ws, size_t ws_size,
                              hipStream_t stream) {
    const float* node_feats = (const float*)d_in[0];
    const float* edge_vec   = (const float*)d_in[1];
    const float* W1         = (const float*)d_in[2];
    const float* W2         = (const float*)d_in[3];
    const int*   edge_src   = (const int*)d_in[4];
    // d_in[5] (edge_dst) unused: segment_sum().sum() == plain sum over edges.
    const int n_edges = in_sizes[4];
    const int n_nodes = in_sizes[0] / 9;

    // ws layout: [block_sums 32KB][wtabf 3*NBP f32][wrec NB*16B][node table N*16B]
    float* block_sums = (float*)d_ws;
    const size_t wtabf_off = 32768;
    const size_t wrec_off  = wtabf_off + ((3 * NBP * 4 + 255) & ~255);
    const size_t tab_off   = wrec_off + NB * 16;
    const size_t need      = tab_off + (size_t)n_nodes * 16;

    if (ws_size >= need) {
        float* wtabf = (float*)((char*)d_ws + wtabf_off);
        uint4* wrec  = (uint4*)((char*)d_ws + wrec_off);
        uint4* tab   = (uint4*)((char*)d_ws + tab_off);
        pack_feats_14<<<(n_nodes + 255) / 256, 256, 0, stream>>>(
            node_feats, tab, n_nodes);
        build_wtable_kernel<<<(NB + 256) / 256, 256, 0, stream>>>(W1, W2, wtabf);
        build_wrec_kernel<<<NB / 256, 256, 0, stream>>>(wtabf, wrec);
        edge_sum_p14w<<<NBLOCKS, NTHREADS, 0, stream>>>(
            (const float4*)edge_vec, (const int4*)edge_src, tab, wrec,
            block_sums, n_edges);
        final_reduce_kernel<<<1, 256, 0, stream>>>(block_sums, (float*)d_out, NBLOCKS);
    } else {
        edge_sum_fallback<<<FB_NBLOCKS, NTHREADS, 0, stream>>>(
            node_feats, edge_vec, W1, W2, edge_src, block_sums, n_edges);
        final_reduce_kernel<<<1, 256, 0, stream>>>(block_sums, (float*)d_out, FB_NBLOCKS);
    }
}

// Round 16
// 46.227 us; speedup vs baseline: 1.2125x; 1.2125x over previous
//
#include <hip/hip_runtime.h>
#include <hip/hip_fp16.h>

#define NTHREADS 256
#define NBLOCKS 2048
#define FB_NBLOCKS 2048
#define NB 1024          // lerp intervals
#define NBP 1040         // padded stride for f32 LUT scratch

// Folded constants (same derivation as R9/R13):
//   KTOT = sqrt(2)*1.14136*e^2 ; CL_l = PATH_C_l * 0.25 / sqrt(10)
//   SH scales folded into packed node values; w_l(r)*CL_l in the r-LUT.
#define KTOT 11.9269705f
#define CL0  0.04564355f
#define CL1  0.02635231f
#define CL2  0.02041241f
#define S3   1.7320508f
#define S5   2.2360680f

__device__ __forceinline__ float fast_rcp(float x) { return __builtin_amdgcn_rcpf(x); }

// ---------- prep 1: node_feats [N][9] f32 -> 16B/node packed record (PROVEN R13) ----------
// bits [0..112): f1s..f8s as fp14 (fp16 rounded, >>2) at 14-bit stride; [112..128): f0 fp16
__global__ __launch_bounds__(256) void pack_feats_14(
    const float* __restrict__ nf, uint4* __restrict__ tab, int n_nodes)
{
    const int n = blockIdx.x * 256 + threadIdx.x;
    if (n >= n_nodes) return;
    const float* f = nf + 9 * (size_t)n;
    const float scale[9] = { 1.0f, S3, S3, S3, S5 * S3, S5 * S3, S5, S5 * S3,
                             0.5f * S5 * S3 };
    unsigned short hs[9];
#pragma unroll
    for (int i = 0; i < 9; ++i) {
        const __half h = __float2half_rn(f[i] * scale[i]);
        hs[i] = *reinterpret_cast<const unsigned short*>(&h);
    }
    unsigned long long c[9];
#pragma unroll
    for (int i = 1; i < 9; ++i)
        c[i] = (unsigned long long)(((unsigned)hs[i] + 2u) >> 2) & 0x3FFFull;
    const unsigned long long lo =
        c[1] | (c[2] << 14) | (c[3] << 28) | (c[4] << 42) | (c[5] << 56);
    const unsigned long long hi =
        (c[5] >> 8) | (c[6] << 6) | (c[7] << 20) | (c[8] << 34) |
        ((unsigned long long)hs[0] << 48);
    tab[n] = make_uint4((unsigned)lo, (unsigned)(lo >> 32),
                        (unsigned)hi, (unsigned)(hi >> 32));
}

// ---------- prep 2a: w_l(r)*CL_l at nodes r=i/NB, i=0..NB (f32 scratch) ----------
__global__ __launch_bounds__(256) void build_wtable_kernel(
    const float* __restrict__ W1, const float* __restrict__ W2,
    float* __restrict__ wtabf)   // [3][NBP]
{
    const int idx = blockIdx.x * 256 + threadIdx.x;
    if (idx > NB) return;
    const float r = (float)idx * (1.0f / (float)NB);

    const float t    = 11.0f * r;
    const int   k0   = (int)t;
    const float frac = t - (float)k0;
    float ea = 0.0f, eb = 0.0f;
    if (k0 >= 1 && k0 <= 10) {
        const float da = fmaf(-frac, frac, 1.0f);
        if (da > 0.0226f) ea = KTOT * __expf(-2.0f * fast_rcp(da));
    }
    if (k0 <= 9) {
        const float db = frac * (2.0f - frac);
        if (db > 0.0226f) eb = KTOT * __expf(-2.0f * fast_rcp(db));
    }
    const int ra = min(max(k0 - 1, 0), 9);
    const int rb = min(k0, 9);

    float w0 = 0.0f, w1 = 0.0f, w2 = 0.0f;
#pragma unroll
    for (int j = 0; j < 16; ++j) {
        const float h = fmaxf(fmaf(ea, W1[ra * 16 + j], eb * W1[rb * 16 + j]), 0.0f);
        w0 = fmaf(h, W2[j * 3 + 0], w0);
        w1 = fmaf(h, W2[j * 3 + 1], w1);
        w2 = fmaf(h, W2[j * 3 + 2], w2);
    }
    wtabf[idx]           = w0 * CL0;
    wtabf[NBP + idx]     = w1 * CL1;
    wtabf[2 * NBP + idx] = w2 * CL2;
}

// ---------- prep 2b: per-interval 16B records {b0,b1,b2, d0,d1,d2} as fp16 ----------
__global__ __launch_bounds__(256) void build_wrec_kernel(
    const float* __restrict__ wtabf, uint4* __restrict__ wrec)
{
    const int i = blockIdx.x * 256 + threadIdx.x;
    if (i >= NB) return;
    const float w0a = wtabf[i],           w0b = wtabf[i + 1];
    const float w1a = wtabf[NBP + i],     w1b = wtabf[NBP + i + 1];
    const float w2a = wtabf[2 * NBP + i], w2b = wtabf[2 * NBP + i + 1];
    auto hbits = [](float v) -> unsigned {
        const __half h = __float2half_rn(v);
        return (unsigned)*reinterpret_cast<const unsigned short*>(&h);
    };
    const unsigned b0 = hbits(w0a), b1 = hbits(w1a), b2 = hbits(w2a);
    const unsigned d0 = hbits(w0b - w0a), d1 = hbits(w1b - w1a), d2 = hbits(w2b - w2a);
    wrec[i] = make_uint4(b0 | (b1 << 16), b2 | (d0 << 16), d1 | (d2 << 16), 0u);
}

// fp14/fp16 decode
__device__ __forceinline__ float cvt14(unsigned c) {
    __half_raw hr; hr.x = (unsigned short)(c << 2);
    return __half2float(*reinterpret_cast<const __half*>(&hr));
}
__device__ __forceinline__ float cvt16(unsigned c) {
    __half_raw hr; hr.x = (unsigned short)(c & 0xFFFFu);
    return __half2float(*reinterpret_cast<const __half*>(&hr));
}
__device__ __forceinline__ unsigned alignb(unsigned hi, unsigned lo, int s) {
    return (lo >> s) | (hi << (32 - s));
}

// ---------- per-edge term: one ds_read_b128 LUT + packed node record g ----------
__device__ __forceinline__ float edge_term(
    float vx, float vy, float vz, uint4 g, const uint4* __restrict__ swq)
{
    const float r2 = fmaf(vx, vx, fmaf(vy, vy, vz * vz));
    const float rs = rsqrtf(fmaxf(r2, 1e-24f));
    const float r  = r2 * rs;
    const float x = vx * rs, y = vy * rs, z = vz * rs;

    const float tb = fminf(r, 1.0f) * (float)NB;
    const int   i  = min((int)tb, NB - 1);
    const float fb = tb - (float)i;
    const uint4 q = swq[i];   // single ds_read_b128
    // q.x = b0|b1<<16 ; q.y = b2|d0<<16 ; q.z = d1|d2<<16
    const float wv0 = fmaf(fb, cvt16(q.y >> 16), cvt16(q.x));
    const float wv1 = fmaf(fb, cvt16(q.z),       cvt16(q.x >> 16));
    const float wv2 = fmaf(fb, cvt16(q.z >> 16), cvt16(q.y));

    // unpack 9 node values from 128 bits (PROVEN R13)
    const float fv1 = cvt14(g.x & 0x3FFFu);
    const float fv2 = cvt14((g.x >> 14) & 0x3FFFu);
    const float fv3 = cvt14(alignb(g.y, g.x, 28) & 0x3FFFu);
    const float fv4 = cvt14((g.y >> 10) & 0x3FFFu);
    const float fv5 = cvt14(alignb(g.z, g.y, 24) & 0x3FFFu);
    const float fv6 = cvt14((g.z >> 6) & 0x3FFFu);
    const float fv7 = cvt14(alignb(g.w, g.z, 20) & 0x3FFFu);
    const float fv8 = cvt14((g.w >> 2) & 0x3FFFu);
    const float f0  = cvt16(g.w >> 16);

    const float dots0 = f0;
    const float dots1 = fmaf(fv1, x, fmaf(fv2, y, fv3 * z));
    const float xx = x * x, yy = y * y, zz = z * z;
    const float dots2 = fmaf(fv4, x * z, fmaf(fv5, x * y,
                        fmaf(fv6, fmaf(-0.5f, xx + zz, yy),
                        fmaf(fv7, y * z, fv8 * (zz - xx)))));

    return fmaf(wv0, dots0, fmaf(wv1, dots1, wv2 * dots2));
}

// ---------- main: R13 structure (2048x256, 4 edges/iter), 1 gather + 1 LDS b128 per edge ----------
__global__ __launch_bounds__(NTHREADS) void edge_sum_p14q(
    const float4* __restrict__ ev4,
    const int4*   __restrict__ src4,
    const uint4*  __restrict__ tab,
    const uint4*  __restrict__ wrec,
    float*        __restrict__ block_sums,
    int n_edges)
{
    __shared__ uint4 swq[NB];   // 16 KB
    const int tid = threadIdx.x;
    for (int i = tid; i < NB; i += NTHREADS) swq[i] = wrec[i];
    __syncthreads();

    float acc = 0.0f;
    const int n_groups = (n_edges + 3) >> 2;
    const int stride = gridDim.x * blockDim.x;
    for (int g = blockIdx.x * blockDim.x + tid; g < n_groups; g += stride) {
        const int e0 = g << 2;
        if (e0 + 3 < n_edges) {
            const float4 a = ev4[3 * (size_t)g + 0];
            const float4 b = ev4[3 * (size_t)g + 1];
            const float4 c = ev4[3 * (size_t)g + 2];
            const int4   s = src4[g];
            const uint4 g0 = tab[s.x];
            const uint4 g1 = tab[s.y];
            const uint4 g2 = tab[s.z];
            const uint4 g3 = tab[s.w];
            acc += edge_term(a.x, a.y, a.z, g0, swq);
            acc += edge_term(a.w, b.x, b.y, g1, swq);
            acc += edge_term(b.z, b.w, c.x, g2, swq);
            acc += edge_term(c.y, c.z, c.w, g3, swq);
        } else {
            const float* evf  = reinterpret_cast<const float*>(ev4);
            const int*   srci = reinterpret_cast<const int*>(src4);
            for (int e = e0; e < n_edges; ++e) {
                acc += edge_term(evf[3 * (size_t)e], evf[3 * (size_t)e + 1],
                                 evf[3 * (size_t)e + 2], tab[srci[e]], swq);
            }
        }
    }

    // deterministic block reduction
#pragma unroll
    for (int off = 1; off < 64; off <<= 1)
        acc += __shfl_xor(acc, off, 64);
    __shared__ float wsum[NTHREADS / 64];
    const int lane = tid & 63, wid = tid >> 6;
    if (lane == 0) wsum[wid] = acc;
    __syncthreads();
    if (tid == 0) {
        float ssum = 0.0f;
#pragma unroll
        for (int w = 0; w < NTHREADS / 64; ++w) ssum += wsum[w];
        block_sums[blockIdx.x] = ssum;
    }
}

// ---------- fallback (round-2 proven path, exact math, f32 scalar gather) ----------
__global__ __launch_bounds__(NTHREADS) void edge_sum_fallback(
    const float* __restrict__ node_feats,
    const float* __restrict__ edge_vec,
    const float* __restrict__ W1,
    const float* __restrict__ W2,
    const int*   __restrict__ edge_src,
    float*       __restrict__ block_sums,
    int n_edges)
{
    __shared__ float4 sW1[10][5];
    float* sW1f = reinterpret_cast<float*>(sW1);
    const int tid = threadIdx.x;
    if (tid < 160) {
        sW1f[(tid >> 4) * 20 + (tid & 15)] = W1[tid];
    } else if (tid < 200) {
        const int i = tid - 160;
        sW1f[(i >> 2) * 20 + 16 + (i & 3)] = 0.0f;
    }
    __syncthreads();

    float w2r[16][3];
#pragma unroll
    for (int j = 0; j < 16; ++j) {
        w2r[j][0] = W2[j * 3 + 0] * CL0;
        w2r[j][1] = W2[j * 3 + 1] * CL1;
        w2r[j][2] = W2[j * 3 + 2] * CL2;
    }

    float acc = 0.0f;
    const int stride = gridDim.x * blockDim.x;
    for (int e = blockIdx.x * blockDim.x + tid; e < n_edges; e += stride) {
        const float vx = edge_vec[3 * (size_t)e + 0];
        const float vy = edge_vec[3 * (size_t)e + 1];
        const float vz = edge_vec[3 * (size_t)e + 2];
        const int   src = edge_src[e];
        const float* f = node_feats + 9 * (size_t)src;
        const float r2 = fmaf(vx, vx, fmaf(vy, vy, vz * vz));
        const float rs = rsqrtf(fmaxf(r2, 1e-24f));
        const float r  = r2 * rs;
        const float x = vx * rs, y = vy * rs, z = vz * rs;
        const float t    = 11.0f * r;
        const int   k0   = (int)t;
        const float frac = t - (float)k0;
        float ea = 0.0f, eb = 0.0f;
        if (k0 >= 1 && k0 <= 10) {
            const float da = fmaf(-frac, frac, 1.0f);
            if (da > 0.0226f) ea = KTOT * __expf(-2.0f * fast_rcp(da));
        }
        if (k0 <= 9) {
            const float db = frac * (2.0f - frac);
            if (db > 0.0226f) eb = KTOT * __expf(-2.0f * fast_rcp(db));
        }
        const int ra = min(max(k0 - 1, 0), 9);
        const int rb = min(k0, 9);
        const float4* rowA = &sW1[ra][0];
        const float4* rowB = &sW1[rb][0];
        float wv0 = 0.0f, wv1 = 0.0f, wv2 = 0.0f;
#pragma unroll
        for (int q = 0; q < 4; ++q) {
            const float4 A = rowA[q];
            const float4 B = rowB[q];
            float h;
            h = fmaxf(fmaf(ea, A.x, eb * B.x), 0.0f);
            wv0 = fmaf(h, w2r[4 * q + 0][0], wv0); wv1 = fmaf(h, w2r[4 * q + 0][1], wv1); wv2 = fmaf(h, w2r[4 * q + 0][2], wv2);
            h = fmaxf(fmaf(ea, A.y, eb * B.y), 0.0f);
            wv0 = fmaf(h, w2r[4 * q + 1][0], wv0); wv1 = fmaf(h, w2r[4 * q + 1][1], wv1); wv2 = fmaf(h, w2r[4 * q + 1][2], wv2);
            h = fmaxf(fmaf(ea, A.z, eb * B.z), 0.0f);
            wv0 = fmaf(h, w2r[4 * q + 2][0], wv0); wv1 = fmaf(h, w2r[4 * q + 2][1], wv1); wv2 = fmaf(h, w2r[4 * q + 2][2], wv2);
            h = fmaxf(fmaf(ea, A.w, eb * B.w), 0.0f);
            wv0 = fmaf(h, w2r[4 * q + 3][0], wv0); wv1 = fmaf(h, w2r[4 * q + 3][1], wv1); wv2 = fmaf(h, w2r[4 * q + 3][2], wv2);
        }
        const float f0 = f[0], f1 = f[1], f2 = f[2], f3 = f[3], f4 = f[4];
        const float f5 = f[5], f6 = f[6], f7 = f[7], f8 = f[8];
        const float dots0 = f0;
        const float dots1 = S3 * fmaf(f1, x, fmaf(f2, y, f3 * z));
        const float xx = x * x, yy = y * y, zz = z * z;
        const float sh20 = S5 * S3 * x * z;
        const float sh21 = S5 * S3 * x * y;
        const float sh22 = S5 * (yy - 0.5f * (xx + zz));
        const float sh23 = S5 * S3 * y * z;
        const float sh24 = S5 * 0.5f * S3 * (zz - xx);
        const float dots2 = fmaf(f4, sh20, fmaf(f5, sh21, fmaf(f6, sh22, fmaf(f7, sh23, f8 * sh24))));
        acc = fmaf(wv0, dots0, acc);
        acc = fmaf(wv1, dots1, acc);
        acc = fmaf(wv2, dots2, acc);
    }
#pragma unroll
    for (int off = 1; off < 64; off <<= 1)
        acc += __shfl_xor(acc, off, 64);
    __shared__ float wsum[NTHREADS / 64];
    const int lane = tid & 63, wid = tid >> 6;
    if (lane == 0) wsum[wid] = acc;
    __syncthreads();
    if (tid == 0) {
        float ssum = 0.0f;
#pragma unroll
        for (int w = 0; w < NTHREADS / 64; ++w) ssum += wsum[w];
        block_sums[blockIdx.x] = ssum;
    }
}

__global__ __launch_bounds__(256) void final_reduce_kernel(
    const float* __restrict__ block_sums, float* __restrict__ out, int n)
{
    const int tid = threadIdx.x;
    float acc = 0.0f;
    for (int i = tid; i < n; i += 256) acc += block_sums[i];
#pragma unroll
    for (int off = 1; off < 64; off <<= 1)
        acc += __shfl_xor(acc, off, 64);
    __shared__ float wsum[4];
    if ((tid & 63) == 0) wsum[tid >> 6] = acc;
    __syncthreads();
    if (tid == 0) out[0] = wsum[0] + wsum[1] + wsum[2] + wsum[3];
}

extern "C" void kernel_launch(void* const* d_in, const int* in_sizes, int n_in,
                              void* d_out, int out_size, void* d_ws, size_t ws_size,
                              hipStream_t stream) {
    const float* node_feats = (const float*)d_in[0];
    const float* edge_vec   = (const float*)d_in[1];
    const float* W1         = (const float*)d_in[2];
    const float* W2         = (const float*)d_in[3];
    const int*   edge_src   = (const int*)d_in[4];
    // d_in[5] (edge_dst) unused: segment_sum().sum() == plain sum over edges.
    const int n_edges = in_sizes[4];
    const int n_nodes = in_sizes[0] / 9;

    // ws layout: [block_sums 32KB][wtabf 3*NBP f32][wrec NB*16B][node table N*16B]
    float* block_sums = (float*)d_ws;
    const size_t wtabf_off = 32768;
    const size_t wrec_off  = wtabf_off + ((3 * NBP * 4 + 255) & ~255);
    const size_t tab_off   = wrec_off + NB * 16;
    const size_t need      = tab_off + (size_t)n_nodes * 16;

    if (ws_size >= need) {
        float* wtabf = (float*)((char*)d_ws + wtabf_off);
        uint4* wrec  = (uint4*)((char*)d_ws + wrec_off);
        uint4* tab   = (uint4*)((char*)d_ws + tab_off);
        pack_feats_14<<<(n_nodes + 255) / 256, 256, 0, stream>>>(
            node_feats, tab, n_nodes);
        build_wtable_kernel<<<(NB + 256) / 256, 256, 0, stream>>>(W1, W2, wtabf);
        build_wrec_kernel<<<NB / 256, 256, 0, stream>>>(wtabf, wrec);
        edge_sum_p14q<<<NBLOCKS, NTHREADS, 0, stream>>>(
            (const float4*)edge_vec, (const int4*)edge_src, tab, wrec,
            block_sums, n_edges);
        final_reduce_kernel<<<1, 256, 0, stream>>>(block_sums, (float*)d_out, NBLOCKS);
    } else {
        edge_sum_fallback<<<FB_NBLOCKS, NTHREADS, 0, stream>>>(
            node_feats, edge_vec, W1, W2, edge_src, block_sums, n_edges);
        final_reduce_kernel<<<1, 256, 0, stream>>>(block_sums, (float*)d_out, FB_NBLOCKS);
    }
}

// Round 17
// 44.804 us; speedup vs baseline: 1.2510x; 1.0318x over previous
//
#include <hip/hip_runtime.h>
#include <hip/hip_fp16.h>

#define NTHREADS 256
#define NBLOCKS 2048
#define FB_NBLOCKS 2048
#define NB 1024          // lerp intervals

// Folded constants (derivation R9/R13):
//   KTOT = sqrt(2)*1.14136*e^2 ; CL_l = PATH_C_l * 0.25 / sqrt(10)
//   SH scales folded into packed node values; w_l(r)*CL_l in the r-LUT.
#define KTOT 11.9269705f
#define CL0  0.04564355f
#define CL1  0.02635231f
#define CL2  0.02041241f
#define S3   1.7320508f
#define S5   2.2360680f

__device__ __forceinline__ float fast_rcp(float x) { return __builtin_amdgcn_rcpf(x); }

// ---------- w_l(r)*CL_l evaluator (exact math, used only in prep) ----------
__device__ __forceinline__ void eval_w(
    float r, const float* __restrict__ W1, const float* __restrict__ W2,
    float& w0, float& w1, float& w2)
{
    const float t    = 11.0f * r;
    const int   k0   = (int)t;
    const float frac = t - (float)k0;
    float ea = 0.0f, eb = 0.0f;
    if (k0 >= 1 && k0 <= 10) {
        const float da = fmaf(-frac, frac, 1.0f);
        if (da > 0.0226f) ea = KTOT * __expf(-2.0f * fast_rcp(da));
    }
    if (k0 <= 9) {
        const float db = frac * (2.0f - frac);
        if (db > 0.0226f) eb = KTOT * __expf(-2.0f * fast_rcp(db));
    }
    const int ra = min(max(k0 - 1, 0), 9);
    const int rb = min(k0, 9);
    w0 = 0.0f; w1 = 0.0f; w2 = 0.0f;
#pragma unroll
    for (int j = 0; j < 16; ++j) {
        const float h = fmaxf(fmaf(ea, W1[ra * 16 + j], eb * W1[rb * 16 + j]), 0.0f);
        w0 = fmaf(h, W2[j * 3 + 0], w0);
        w1 = fmaf(h, W2[j * 3 + 1], w1);
        w2 = fmaf(h, W2[j * 3 + 2], w2);
    }
    w0 *= CL0; w1 *= CL1; w2 *= CL2;
}

// ---------- fused prep: node packing + LUT records in ONE kernel ----------
// blocks [0, pack_blocks): pack node_feats -> 16B fp14 records (PROVEN R13/R16)
// blocks [pack_blocks, pack_blocks+4): build wrec[i] for i in [0,1024)
__global__ __launch_bounds__(256) void prep_kernel(
    const float* __restrict__ nf,
    const float* __restrict__ W1, const float* __restrict__ W2,
    uint4* __restrict__ tab, uint4* __restrict__ wrec,
    int n_nodes, int pack_blocks)
{
    const int tid = threadIdx.x;
    if ((int)blockIdx.x < pack_blocks) {
        const int n = blockIdx.x * 256 + tid;
        if (n >= n_nodes) return;
        const float* f = nf + 9 * (size_t)n;
        const float scale[9] = { 1.0f, S3, S3, S3, S5 * S3, S5 * S3, S5, S5 * S3,
                                 0.5f * S5 * S3 };
        unsigned short hs[9];
#pragma unroll
        for (int i = 0; i < 9; ++i) {
            const __half h = __float2half_rn(f[i] * scale[i]);
            hs[i] = *reinterpret_cast<const unsigned short*>(&h);
        }
        unsigned long long c[9];
#pragma unroll
        for (int i = 1; i < 9; ++i)
            c[i] = (unsigned long long)(((unsigned)hs[i] + 2u) >> 2) & 0x3FFFull;
        const unsigned long long lo =
            c[1] | (c[2] << 14) | (c[3] << 28) | (c[4] << 42) | (c[5] << 56);
        const unsigned long long hi =
            (c[5] >> 8) | (c[6] << 6) | (c[7] << 20) | (c[8] << 34) |
            ((unsigned long long)hs[0] << 48);
        tab[n] = make_uint4((unsigned)lo, (unsigned)(lo >> 32),
                            (unsigned)hi, (unsigned)(hi >> 32));
    } else {
        const int i = ((int)blockIdx.x - pack_blocks) * 256 + tid;
        if (i >= NB) return;
        float w0a, w1a, w2a, w0b, w1b, w2b;
        eval_w((float)i       * (1.0f / (float)NB), W1, W2, w0a, w1a, w2a);
        eval_w((float)(i + 1) * (1.0f / (float)NB), W1, W2, w0b, w1b, w2b);
        auto hbits = [](float v) -> unsigned {
            const __half h = __float2half_rn(v);
            return (unsigned)*reinterpret_cast<const unsigned short*>(&h);
        };
        const unsigned b0 = hbits(w0a), b1 = hbits(w1a), b2 = hbits(w2a);
        const unsigned d0 = hbits(w0b - w0a), d1 = hbits(w1b - w1a), d2 = hbits(w2b - w2a);
        wrec[i] = make_uint4(b0 | (b1 << 16), b2 | (d0 << 16), d1 | (d2 << 16), 0u);
    }
}

// fp14/fp16 decode
__device__ __forceinline__ float cvt14(unsigned c) {
    __half_raw hr; hr.x = (unsigned short)(c << 2);
    return __half2float(*reinterpret_cast<const __half*>(&hr));
}
__device__ __forceinline__ float cvt16(unsigned c) {
    __half_raw hr; hr.x = (unsigned short)(c & 0xFFFFu);
    return __half2float(*reinterpret_cast<const __half*>(&hr));
}
__device__ __forceinline__ unsigned alignb(unsigned hi, unsigned lo, int s) {
    return (lo >> s) | (hi << (32 - s));
}

// ---------- per-edge term: one ds_read_b128 LUT + packed node record g (PROVEN R16) ----------
__device__ __forceinline__ float edge_term(
    float vx, float vy, float vz, uint4 g, const uint4* __restrict__ swq)
{
    const float r2 = fmaf(vx, vx, fmaf(vy, vy, vz * vz));
    const float rs = rsqrtf(fmaxf(r2, 1e-24f));
    const float r  = r2 * rs;
    const float x = vx * rs, y = vy * rs, z = vz * rs;

    const float tb = fminf(r, 1.0f) * (float)NB;
    const int   i  = min((int)tb, NB - 1);
    const float fb = tb - (float)i;
    const uint4 q = swq[i];   // single ds_read_b128
    const float wv0 = fmaf(fb, cvt16(q.y >> 16), cvt16(q.x));
    const float wv1 = fmaf(fb, cvt16(q.z),       cvt16(q.x >> 16));
    const float wv2 = fmaf(fb, cvt16(q.z >> 16), cvt16(q.y));

    const float fv1 = cvt14(g.x & 0x3FFFu);
    const float fv2 = cvt14((g.x >> 14) & 0x3FFFu);
    const float fv3 = cvt14(alignb(g.y, g.x, 28) & 0x3FFFu);
    const float fv4 = cvt14((g.y >> 10) & 0x3FFFu);
    const float fv5 = cvt14(alignb(g.z, g.y, 24) & 0x3FFFu);
    const float fv6 = cvt14((g.z >> 6) & 0x3FFFu);
    const float fv7 = cvt14(alignb(g.w, g.z, 20) & 0x3FFFu);
    const float fv8 = cvt14((g.w >> 2) & 0x3FFFu);
    const float f0  = cvt16(g.w >> 16);

    const float dots0 = f0;
    const float dots1 = fmaf(fv1, x, fmaf(fv2, y, fv3 * z));
    const float xx = x * x, yy = y * y, zz = z * z;
    const float dots2 = fmaf(fv4, x * z, fmaf(fv5, x * y,
                        fmaf(fv6, fmaf(-0.5f, xx + zz, yy),
                        fmaf(fv7, y * z, fv8 * (zz - xx)))));

    return fmaf(wv0, dots0, fmaf(wv1, dots1, wv2 * dots2));
}

// ---------- main: unroll-2 over the grid-stride (both iterations' chains overlapped) ----------
__global__ __launch_bounds__(NTHREADS) void edge_sum_u2(
    const float4* __restrict__ ev4,
    const int4*   __restrict__ src4,
    const uint4*  __restrict__ tab,
    const uint4*  __restrict__ wrec,
    float*        __restrict__ block_sums,
    int n_edges)
{
    __shared__ uint4 swq[NB];   // 16 KB
    const int tid = threadIdx.x;
    for (int i = tid; i < NB; i += NTHREADS) swq[i] = wrec[i];
    __syncthreads();

    float acc = 0.0f;
    const int n_groups = (n_edges + 3) >> 2;
    const int stride = gridDim.x * blockDim.x;
    const int g1 = blockIdx.x * blockDim.x + tid;
    const int g2 = g1 + stride;
    const bool v1 = (g1 < n_groups) && ((g1 << 2) + 4 <= n_edges);
    const bool v2 = (g2 < n_groups) && ((g2 << 2) + 4 <= n_edges);

    // stage 1: all stream loads for both groups
    float4 a1, b1, c1, a2, b2, c2;
    int4 s1, s2;
    if (v1) {
        a1 = ev4[3 * (size_t)g1 + 0];
        b1 = ev4[3 * (size_t)g1 + 1];
        c1 = ev4[3 * (size_t)g1 + 2];
        s1 = src4[g1];
    }
    if (v2) {
        a2 = ev4[3 * (size_t)g2 + 0];
        b2 = ev4[3 * (size_t)g2 + 1];
        c2 = ev4[3 * (size_t)g2 + 2];
        s2 = src4[g2];
    }
    // stage 2: all 8 gathers
    uint4 t0, t1, t2, t3, t4, t5, t6, t7;
    if (v1) { t0 = tab[s1.x]; t1 = tab[s1.y]; t2 = tab[s1.z]; t3 = tab[s1.w]; }
    if (v2) { t4 = tab[s2.x]; t5 = tab[s2.y]; t6 = tab[s2.z]; t7 = tab[s2.w]; }
    // stage 3: compute
    if (v1) {
        acc += edge_term(a1.x, a1.y, a1.z, t0, swq);
        acc += edge_term(a1.w, b1.x, b1.y, t1, swq);
        acc += edge_term(b1.z, b1.w, c1.x, t2, swq);
        acc += edge_term(c1.y, c1.z, c1.w, t3, swq);
    }
    if (v2) {
        acc += edge_term(a2.x, a2.y, a2.z, t4, swq);
        acc += edge_term(a2.w, b2.x, b2.y, t5, swq);
        acc += edge_term(b2.z, b2.w, c2.x, t6, swq);
        acc += edge_term(c2.y, c2.z, c2.w, t7, swq);
    }

    // generic coverage: groups beyond the unrolled pair (only if grid doesn't cover),
    // plus partial last group (n_edges % 4 != 0)
    for (int g = g1 + 2 * stride; g < n_groups; g += stride) {
        const int e0 = g << 2;
        if (e0 + 4 <= n_edges) {
            const float4 a = ev4[3 * (size_t)g + 0];
            const float4 b = ev4[3 * (size_t)g + 1];
            const float4 c = ev4[3 * (size_t)g + 2];
            const int4   s = src4[g];
            const uint4 q0 = tab[s.x];
            const uint4 q1 = tab[s.y];
            const uint4 q2 = tab[s.z];
            const uint4 q3 = tab[s.w];
            acc += edge_term(a.x, a.y, a.z, q0, swq);
            acc += edge_term(a.w, b.x, b.y, q1, swq);
            acc += edge_term(b.z, b.w, c.x, q2, swq);
            acc += edge_term(c.y, c.z, c.w, q3, swq);
        } else {
            const float* evf  = reinterpret_cast<const float*>(ev4);
            const int*   srci = reinterpret_cast<const int*>(src4);
            for (int e = e0; e < n_edges; ++e)
                acc += edge_term(evf[3 * (size_t)e], evf[3 * (size_t)e + 1],
                                 evf[3 * (size_t)e + 2], tab[srci[e]], swq);
        }
    }
    if (g1 < n_groups && !v1) {
        const float* evf  = reinterpret_cast<const float*>(ev4);
        const int*   srci = reinterpret_cast<const int*>(src4);
        for (int e = (g1 << 2); e < n_edges; ++e)
            acc += edge_term(evf[3 * (size_t)e], evf[3 * (size_t)e + 1],
                             evf[3 * (size_t)e + 2], tab[srci[e]], swq);
    }
    if (g2 < n_groups && !v2) {
        const float* evf  = reinterpret_cast<const float*>(ev4);
        const int*   srci = reinterpret_cast<const int*>(src4);
        for (int e = (g2 << 2); e < n_edges; ++e)
            acc += edge_term(evf[3 * (size_t)e], evf[3 * (size_t)e + 1],
                             evf[3 * (size_t)e + 2], tab[srci[e]], swq);
    }

    // deterministic block reduction
#pragma unroll
    for (int off = 1; off < 64; off <<= 1)
        acc += __shfl_xor(acc, off, 64);
    __shared__ float wsum[NTHREADS / 64];
    const int lane = tid & 63, wid = tid >> 6;
    if (lane == 0) wsum[wid] = acc;
    __syncthreads();
    if (tid == 0) {
        float ssum = 0.0f;
#pragma unroll
        for (int w = 0; w < NTHREADS / 64; ++w) ssum += wsum[w];
        block_sums[blockIdx.x] = ssum;
    }
}

// ---------- fallback (round-2 proven path, exact math, f32 scalar gather) ----------
__global__ __launch_bounds__(NTHREADS) void edge_sum_fallback(
    const float* __restrict__ node_feats,
    const float* __restrict__ edge_vec,
    const float* __restrict__ W1,
    const float* __restrict__ W2,
    const int*   __restrict__ edge_src,
    float*       __restrict__ block_sums,
    int n_edges)
{
    __shared__ float4 sW1[10][5];
    float* sW1f = reinterpret_cast<float*>(sW1);
    const int tid = threadIdx.x;
    if (tid < 160) {
        sW1f[(tid >> 4) * 20 + (tid & 15)] = W1[tid];
    } else if (tid < 200) {
        const int i = tid - 160;
        sW1f[(i >> 2) * 20 + 16 + (i & 3)] = 0.0f;
    }
    __syncthreads();

    float w2r[16][3];
#pragma unroll
    for (int j = 0; j < 16; ++j) {
        w2r[j][0] = W2[j * 3 + 0] * CL0;
        w2r[j][1] = W2[j * 3 + 1] * CL1;
        w2r[j][2] = W2[j * 3 + 2] * CL2;
    }

    float acc = 0.0f;
    const int stride = gridDim.x * blockDim.x;
    for (int e = blockIdx.x * blockDim.x + tid; e < n_edges; e += stride) {
        const float vx = edge_vec[3 * (size_t)e + 0];
        const float vy = edge_vec[3 * (size_t)e + 1];
        const float vz = edge_vec[3 * (size_t)e + 2];
        const int   src = edge_src[e];
        const float* f = node_feats + 9 * (size_t)src;
        const float r2 = fmaf(vx, vx, fmaf(vy, vy, vz * vz));
        const float rs = rsqrtf(fmaxf(r2, 1e-24f));
        const float r  = r2 * rs;
        const float x = vx * rs, y = vy * rs, z = vz * rs;
        const float t    = 11.0f * r;
        const int   k0   = (int)t;
        const float frac = t - (float)k0;
        float ea = 0.0f, eb = 0.0f;
        if (k0 >= 1 && k0 <= 10) {
            const float da = fmaf(-frac, frac, 1.0f);
            if (da > 0.0226f) ea = KTOT * __expf(-2.0f * fast_rcp(da));
        }
        if (k0 <= 9) {
            const float db = frac * (2.0f - frac);
            if (db > 0.0226f) eb = KTOT * __expf(-2.0f * fast_rcp(db));
        }
        const int ra = min(max(k0 - 1, 0), 9);
        const int rb = min(k0, 9);
        const float4* rowA = &sW1[ra][0];
        const float4* rowB = &sW1[rb][0];
        float wv0 = 0.0f, wv1 = 0.0f, wv2 = 0.0f;
#pragma unroll
        for (int q = 0; q < 4; ++q) {
            const float4 A = rowA[q];
            const float4 B = rowB[q];
            float h;
            h = fmaxf(fmaf(ea, A.x, eb * B.x), 0.0f);
            wv0 = fmaf(h, w2r[4 * q + 0][0], wv0); wv1 = fmaf(h, w2r[4 * q + 0][1], wv1); wv2 = fmaf(h, w2r[4 * q + 0][2], wv2);
            h = fmaxf(fmaf(ea, A.y, eb * B.y), 0.0f);
            wv0 = fmaf(h, w2r[4 * q + 1][0], wv0); wv1 = fmaf(h, w2r[4 * q + 1][1], wv1); wv2 = fmaf(h, w2r[4 * q + 1][2], wv2);
            h = fmaxf(fmaf(ea, A.z, eb * B.z), 0.0f);
            wv0 = fmaf(h, w2r[4 * q + 2][0], wv0); wv1 = fmaf(h, w2r[4 * q + 2][1], wv1); wv2 = fmaf(h, w2r[4 * q + 2][2], wv2);
            h = fmaxf(fmaf(ea, A.w, eb * B.w), 0.0f);
            wv0 = fmaf(h, w2r[4 * q + 3][0], wv0); wv1 = fmaf(h, w2r[4 * q + 3][1], wv1); wv2 = fmaf(h, w2r[4 * q + 3][2], wv2);
        }
        const float f0 = f[0], f1 = f[1], f2 = f[2], f3 = f[3], f4 = f[4];
        const float f5 = f[5], f6 = f[6], f7 = f[7], f8 = f[8];
        const float dots0 = f0;
        const float dots1 = S3 * fmaf(f1, x, fmaf(f2, y, f3 * z));
        const float xx = x * x, yy = y * y, zz = z * z;
        const float sh20 = S5 * S3 * x * z;
        const float sh21 = S5 * S3 * x * y;
        const float sh22 = S5 * (yy - 0.5f * (xx + zz));
        const float sh23 = S5 * S3 * y * z;
        const float sh24 = S5 * 0.5f * S3 * (zz - xx);
        const float dots2 = fmaf(f4, sh20, fmaf(f5, sh21, fmaf(f6, sh22, fmaf(f7, sh23, f8 * sh24))));
        acc = fmaf(wv0, dots0, acc);
        acc = fmaf(wv1, dots1, acc);
        acc = fmaf(wv2, dots2, acc);
    }
#pragma unroll
    for (int off = 1; off < 64; off <<= 1)
        acc += __shfl_xor(acc, off, 64);
    __shared__ float wsum[NTHREADS / 64];
    const int lane = tid & 63, wid = tid >> 6;
    if (lane == 0) wsum[wid] = acc;
    __syncthreads();
    if (tid == 0) {
        float ssum = 0.0f;
#pragma unroll
        for (int w = 0; w < NTHREADS / 64; ++w) ssum += wsum[w];
        block_sums[blockIdx.x] = ssum;
    }
}

__global__ __launch_bounds__(256) void final_reduce_kernel(
    const float* __restrict__ block_sums, float* __restrict__ out, int n)
{
    const int tid = threadIdx.x;
    float acc = 0.0f;
    for (int i = tid; i < n; i += 256) acc += block_sums[i];
#pragma unroll
    for (int off = 1; off < 64; off <<= 1)
        acc += __shfl_xor(acc, off, 64);
    __shared__ float wsum[4];
    if ((tid & 63) == 0) wsum[tid >> 6] = acc;
    __syncthreads();
    if (tid == 0) out[0] = wsum[0] + wsum[1] + wsum[2] + wsum[3];
}

extern "C" void kernel_launch(void* const* d_in, const int* in_sizes, int n_in,
                              void* d_out, int out_size, void* d_ws, size_t ws_size,
                              hipStream_t stream) {
    const float* node_feats = (const float*)d_in[0];
    const float* edge_vec   = (const float*)d_in[1];
    const float* W1         = (const float*)d_in[2];
    const float* W2         = (const float*)d_in[3];
    const int*   edge_src   = (const int*)d_in[4];
    // d_in[5] (edge_dst) unused: segment_sum().sum() == plain sum over edges.
    const int n_edges = in_sizes[4];
    const int n_nodes = in_sizes[0] / 9;

    // ws layout: [block_sums 32KB][wrec NB*16B][node table N*16B]
    float* block_sums = (float*)d_ws;
    const size_t wrec_off = 32768;
    const size_t tab_off  = wrec_off + NB * 16;
    const size_t need     = tab_off + (size_t)n_nodes * 16;

    if (ws_size >= need) {
        uint4* wrec = (uint4*)((char*)d_ws + wrec_off);
        uint4* tab  = (uint4*)((char*)d_ws + tab_off);
        const int pack_blocks = (n_nodes + 255) / 256;
        const int lut_blocks  = NB / 256;   // 4
        prep_kernel<<<pack_blocks + lut_blocks, 256, 0, stream>>>(
            node_feats, W1, W2, tab, wrec, n_nodes, pack_blocks);
        edge_sum_u2<<<NBLOCKS, NTHREADS, 0, stream>>>(
            (const float4*)edge_vec, (const int4*)edge_src, tab, wrec,
            block_sums, n_edges);
        final_reduce_kernel<<<1, 256, 0, stream>>>(block_sums, (float*)d_out, NBLOCKS);
    } else {
        edge_sum_fallback<<<FB_NBLOCKS, NTHREADS, 0, stream>>>(
            node_feats, edge_vec, W1, W2, edge_src, block_sums, n_edges);
        final_reduce_kernel<<<1, 256, 0, stream>>>(block_sums, (float*)d_out, FB_NBLOCKS);
    }
}